// Round 1
// 178.562 us; speedup vs baseline: 1.3735x; 1.3735x over previous
//
#include <hip/hip_runtime.h>

#define KTOT 65536
#define QN 16
#define DN 64
#define BN 8
#define TILE 256

// smem layout (floats)
#define QS_OFF 0                    // q scaled: [16][64]            = 1024
#define KT_OFF 1024                 // K half-tile swizzled [256][32] = 8192  (reused for U-reduce)
#define A_OFF  9216                 // attn tile [16][256]            = 4096  (reused for nacc-reduce)
#define SMEM_FLOATS 13312           // 53,248 B -> 3 blocks/CU

// ---------------- Fused: QK^T + softmax(Q) + attn write + PV partials + norm partials ----------------
__global__ __launch_bounds__(256, 3) void fused_attn(
    const float* __restrict__ query, const float* __restrict__ key,
    const float* __restrict__ value, float* __restrict__ attn,
    float* __restrict__ normp, float* __restrict__ upart,
    int NCH, int ntiles)
{
    __shared__ float smem[SMEM_FLOATS];
    const int b    = blockIdx.y;
    const int c    = blockIdx.x;
    const int tid  = threadIdx.x;
    const int wv   = tid >> 6;
    const int lane = tid & 63;

    // Q -> LDS, pre-scaled by 1/sqrt(64)
    {
        float4 qv = reinterpret_cast<const float4*>(query + (size_t)b * QN * DN)[tid];
        qv.x *= 0.125f; qv.y *= 0.125f; qv.z *= 0.125f; qv.w *= 0.125f;
        reinterpret_cast<float4*>(&smem[QS_OFF])[tid] = qv;
    }

    float U[QN], nacc[QN];
    #pragma unroll
    for (int q = 0; q < QN; ++q) { U[q] = 0.f; nacc[q] = 0.f; }

    const int chunk = ntiles * TILE;

    for (int t = 0; t < ntiles; ++t) {
        const int krow0 = c * chunk + t * TILE;                 // within this batch
        const float4* kbase = reinterpret_cast<const float4*>(
            key + ((size_t)b * KTOT + krow0) * DN);             // row stride = 16 float4

        float s[QN];
        #pragma unroll
        for (int q = 0; q < QN; ++q) s[q] = 0.f;

        float4 stg[8];

        // ---- stage d-half 0: coalesced loads (each instr covers 8 full 128B lines) ----
        #pragma unroll
        for (int j = 0; j < 8; ++j) {
            const int o = j * 256 + tid, r = o >> 3, cc = o & 7;
            stg[j] = kbase[r * 16 + cc];
        }
        __syncthreads();                                        // prev readers of kt / a_lds done
        #pragma unroll
        for (int j = 0; j < 8; ++j) {
            const int o = j * 256 + tid, r = o >> 3, cc = o & 7;
            *reinterpret_cast<float4*>(&smem[KT_OFF + r * 32 + ((cc ^ (r & 7)) << 2)]) = stg[j];
        }
        __syncthreads();

        // issue d-half-1 loads early so HBM latency hides under dot0
        #pragma unroll
        for (int j = 0; j < 8; ++j) {
            const int o = j * 256 + tid, r = o >> 3, cc = o & 7;
            stg[j] = kbase[r * 16 + 8 + cc];
        }

        // ---- dot, d-half 0: thread owns row tid; swizzled read is bank-balanced ----
        #pragma unroll
        for (int i = 0; i < 8; ++i) {
            const float4 kv = *reinterpret_cast<const float4*>(
                &smem[KT_OFF + tid * 32 + ((i ^ (tid & 7)) << 2)]);
            #pragma unroll
            for (int q = 0; q < QN; ++q) {
                const float4 qv = *reinterpret_cast<const float4*>(
                    &smem[QS_OFF + q * DN + i * 4]);            // uniform -> LDS broadcast
                s[q] = fmaf(kv.x, qv.x, s[q]);
                s[q] = fmaf(kv.y, qv.y, s[q]);
                s[q] = fmaf(kv.z, qv.z, s[q]);
                s[q] = fmaf(kv.w, qv.w, s[q]);
            }
        }
        __syncthreads();
        #pragma unroll
        for (int j = 0; j < 8; ++j) {
            const int o = j * 256 + tid, r = o >> 3, cc = o & 7;
            *reinterpret_cast<float4*>(&smem[KT_OFF + r * 32 + ((cc ^ (r & 7)) << 2)]) = stg[j];
        }
        __syncthreads();

        // ---- dot, d-half 1 ----
        #pragma unroll
        for (int i = 0; i < 8; ++i) {
            const float4 kv = *reinterpret_cast<const float4*>(
                &smem[KT_OFF + tid * 32 + ((i ^ (tid & 7)) << 2)]);
            #pragma unroll
            for (int q = 0; q < QN; ++q) {
                const float4 qv = *reinterpret_cast<const float4*>(
                    &smem[QS_OFF + q * DN + 32 + i * 4]);
                s[q] = fmaf(kv.x, qv.x, s[q]);
                s[q] = fmaf(kv.y, qv.y, s[q]);
                s[q] = fmaf(kv.z, qv.z, s[q]);
                s[q] = fmaf(kv.w, qv.w, s[q]);
            }
        }

        // ---- softmax over the 16 queries (thread-local), attn write, a_lds, norm acc ----
        float m = s[0];
        #pragma unroll
        for (int q = 1; q < QN; ++q) m = fmaxf(m, s[q]);
        float e[QN], sum = 0.f;
        #pragma unroll
        for (int q = 0; q < QN; ++q) { e[q] = __expf(s[q] - m); sum += e[q]; }
        const float inv = 1.0f / sum;

        float* ab = attn + (size_t)b * QN * KTOT + krow0 + tid;
        #pragma unroll
        for (int q = 0; q < QN; ++q) {
            const float a = e[q] * inv;
            ab[(size_t)q * KTOT] = a;                           // lanes consecutive k -> coalesced
            smem[A_OFF + q * TILE + tid] = a;                   // 2-way bank = free
            nacc[q] += a;
        }
        __syncthreads();

        // ---- phase B: U[q][lane=d] += a[q][k] * v[k][d], wave owns 64 rows ----
        const int kl0 = wv * 64;
        const float* vrow = value + ((size_t)b * KTOT + krow0 + kl0) * DN + lane;
        #pragma unroll 2
        for (int kk = 0; kk < 64; kk += 4) {
            const float v0 = vrow[(size_t)(kk + 0) * DN];       // 256B/instr coalesced
            const float v1 = vrow[(size_t)(kk + 1) * DN];
            const float v2 = vrow[(size_t)(kk + 2) * DN];
            const float v3 = vrow[(size_t)(kk + 3) * DN];
            #pragma unroll
            for (int qh = 0; qh < 2; ++qh) {
                float4 av[8];
                #pragma unroll
                for (int q = 0; q < 8; ++q)
                    av[q] = *reinterpret_cast<const float4*>(
                        &smem[A_OFF + (qh * 8 + q) * TILE + kl0 + kk]);  // uniform broadcast
                #pragma unroll
                for (int q = 0; q < 8; ++q) {
                    U[qh * 8 + q] = fmaf(av[q].x, v0, U[qh * 8 + q]);
                    U[qh * 8 + q] = fmaf(av[q].y, v1, U[qh * 8 + q]);
                    U[qh * 8 + q] = fmaf(av[q].z, v2, U[qh * 8 + q]);
                    U[qh * 8 + q] = fmaf(av[q].w, v3, U[qh * 8 + q]);
                }
            }
        }
    }

    // ---- block reductions: U across 4 waves (KT region), nacc across 256 threads (A region) ----
    __syncthreads();
    #pragma unroll
    for (int q = 0; q < QN; ++q)
        smem[KT_OFF + (wv * QN + q) * DN + lane] = U[q];
    #pragma unroll
    for (int q = 0; q < QN; ++q) {
        #pragma unroll
        for (int off = 1; off < 64; off <<= 1)
            nacc[q] += __shfl_xor(nacc[q], off, 64);
    }
    if (lane == 0) {
        #pragma unroll
        for (int q = 0; q < QN; ++q) smem[A_OFF + wv * QN + q] = nacc[q];
    }
    __syncthreads();

    {
        const int q = tid >> 4, d0 = (tid & 15) * 4;
        const float4 r0 = *reinterpret_cast<const float4*>(&smem[KT_OFF + (0 * QN + q) * DN + d0]);
        const float4 r1 = *reinterpret_cast<const float4*>(&smem[KT_OFF + (1 * QN + q) * DN + d0]);
        const float4 r2 = *reinterpret_cast<const float4*>(&smem[KT_OFF + (2 * QN + q) * DN + d0]);
        const float4 r3 = *reinterpret_cast<const float4*>(&smem[KT_OFF + (3 * QN + q) * DN + d0]);
        float4 rs;
        rs.x = r0.x + r1.x + r2.x + r3.x;
        rs.y = r0.y + r1.y + r2.y + r3.y;
        rs.z = r0.z + r1.z + r2.z + r3.z;
        rs.w = r0.w + r1.w + r2.w + r3.w;
        *reinterpret_cast<float4*>(
            &upart[(((size_t)b * NCH + c) * QN + q) * DN + d0]) = rs;
        if (tid < QN)
            normp[((size_t)b * NCH + c) * QN + tid] =
                smem[A_OFF + tid] + smem[A_OFF + QN + tid] +
                smem[A_OFF + 2 * QN + tid] + smem[A_OFF + 3 * QN + tid];
    }
}

// ---------------- Finalize: out[b][q][d] = sum_c U / (sum_c norm + eps); grid (8,16) ----------------
__global__ __launch_bounds__(256) void k3_fin(
    const float* __restrict__ upart, const float* __restrict__ normp,
    float* __restrict__ out, int NCH)
{
    const int b = blockIdx.x, q = blockIdx.y;
    const int tid = threadIdx.x;
    const int wv = tid >> 6, lane = tid & 63;

    // norm: one partial per thread, wave-reduce, cross-wave via LDS
    float nv = 0.f;
    for (int c = tid; c < NCH; c += 256)
        nv += normp[((size_t)b * NCH + c) * QN + q];
    #pragma unroll
    for (int off = 1; off < 64; off <<= 1) nv += __shfl_xor(nv, off, 64);
    __shared__ float nred[4];
    if (lane == 0) nred[wv] = nv;

    // U: wave wv strides chunks, lane = d (coalesced 256B/instr)
    float acc = 0.f;
    for (int c = wv; c < NCH; c += 4)
        acc += upart[(((size_t)b * NCH + c) * QN + q) * DN + lane];
    __shared__ float ured[4][DN];
    ured[wv][lane] = acc;
    __syncthreads();

    if (tid < DN) {
        const float n   = nred[0] + nred[1] + nred[2] + nred[3];
        const float inv = 1.0f / (n + 1e-8f);
        const float u   = ured[0][tid] + ured[1][tid] + ured[2][tid] + ured[3][tid];
        out[((size_t)b * QN + q) * DN + tid] = u * inv;
    }
}

extern "C" void kernel_launch(void* const* d_in, const int* in_sizes, int n_in,
                              void* d_out, int out_size, void* d_ws, size_t ws_size,
                              hipStream_t stream)
{
    const float* query = (const float*)d_in[0];
    const float* key   = (const float*)d_in[1];
    const float* value = (const float*)d_in[2];

    float* out  = (float*)d_out;                          // [8,16,64]
    float* attn = (float*)d_out + (size_t)BN * QN * DN;   // [8,1,16,65536]

    int NCH = 256;                                        // chunks per batch (blocks = NCH*8)
    while (NCH > 8 && (size_t)NCH * BN * QN * (DN + 1) * 4 > ws_size) NCH >>= 1;
    const int ntiles = (KTOT / NCH) / TILE;

    float* normp = (float*)d_ws;                          // [8][NCH][16]
    float* upart = (float*)d_ws + (size_t)NCH * BN * QN;  // [8][NCH][16][64]

    fused_attn<<<dim3(NCH, BN), 256, 0, stream>>>(query, key, value, attn,
                                                  normp, upart, NCH, ntiles);
    k3_fin   <<<dim3(BN, QN), 256, 0, stream>>>(upart, normp, out, NCH);
}